// Round 1
// baseline (135.517 us; speedup 1.0000x reference)
//
#include <hip/hip_runtime.h>
#include <hip/hip_bf16.h>

#define Bb 128
#define Tt 1024
#define Ff 128
#define Kk 32
#define KE 36          // g LDS row stride (floats)
#define LOG32 3.4657359027997265f

typedef __attribute__((ext_vector_type(8))) short bf16x8;
typedef __attribute__((ext_vector_type(4))) float f32x4;
typedef __attribute__((ext_vector_type(16))) float f32x16;

__device__ __forceinline__ float bf2f(unsigned u) {
    return __uint_as_float(u << 16);
}
// packed f32x2 -> bf16x2 (v_cvt_pk_bf16_f32 on gfx950)
__device__ __forceinline__ unsigned bfpk2(float a, float b) {
    __hip_bfloat162 h = __float22bfloat162_rn(make_float2(a, b));
    unsigned u;
    __builtin_memcpy(&u, &h, sizeof(u));
    return u;
}
// v_permlane32_swap_b32: a.hi-lanes <-> b.lo-lanes.
// after: a = [a.lo | b.lo(from lanes 0-31)], b = [a.hi(old) | b.hi]
__device__ __forceinline__ void plswap(unsigned &a, unsigned &b) {
    asm("v_permlane32_swap_b32 %0, %1" : "+v"(a), "+v"(b));
}

// ---------------------------------------------------------------------------
// Kernel 1: one 64-lane wave per (batch, chunk-of-32-steps).
//   Emission rows t0..t0+31 via 16x16x32 MFMAs -> g = exp(em-log32) in gl.
//   Chain S <- diag(g_t) * E^T * S runs ENTIRELY IN REGISTERS with
//   32x32x16 MFMA: state S kept as B-fragments; C->B relayout is
//   8 cvt_pk + 4 v_permlane32_swap_b32 per step (no LDS round trip).
//   diag(g) folded into the A operand: A = g[lane&31] * E^T (off-path).
//   Final S stored straight to SQ (coalesced 64B-per-row-half u16 stores).
// ---------------------------------------------------------------------------
__global__ __launch_bounds__(64, 4) void chunk_kernel(
    const float* __restrict__ inp, const int* __restrict__ mask,
    const float* __restrict__ W, const float* __restrict__ trans,
    unsigned short* __restrict__ SQ, float* __restrict__ out)
{
    __shared__ __align__(16) float gl[32 * KE];
    const int lane = threadIdx.x & 63;
    const int q = (lane >> 4) & 3, n = lane & 15;   // 16x16 emission indexing
    const int c32 = lane & 31, hi = lane >> 5;      // 32x32 chain indexing
    const int b = blockIdx.x >> 5, c = blockIdx.x & 31;
    const int t0 = c * 32;

    if (blockIdx.x == 0 && lane == 0) out[0] = 0.f;

    // 32-step mask bits (t=0 is the init state, never a step)
    const int* mbp = mask + (long)b * Tt;
    unsigned mbits = (unsigned)__ballot(mbp[t0 + c32] != 0);  // bit l == bit l+32
    if (c == 0) mbits &= ~1u;

    // ---- W bf16 fragments, hoisted once (serve both 16-row emission tiles) ----
    bf16x8 Wlo[4], Whi[4];
    #pragma unroll
    for (int kt = 0; kt < 4; ++kt) {
        const int f0 = kt * 32 + q * 8;
        float wl[8], wh[8];
        #pragma unroll
        for (int jj = 0; jj < 8; ++jj) {
            wl[jj] = W[(f0 + jj) * Kk + n];
            wh[jj] = W[(f0 + jj) * Kk + 16 + n];
        }
        uint4 uc = make_uint4(bfpk2(wl[0], wl[1]), bfpk2(wl[2], wl[3]),
                              bfpk2(wl[4], wl[5]), bfpk2(wl[6], wl[7]));
        uint4 ud = make_uint4(bfpk2(wh[0], wh[1]), bfpk2(wh[2], wh[3]),
                              bfpk2(wh[4], wh[5]), bfpk2(wh[6], wh[7]));
        Wlo[kt] = __builtin_bit_cast(bf16x8, uc);
        Whi[kt] = __builtin_bit_cast(bf16x8, ud);
    }

    // ---- emission rows t0..t0+31 (two 16-row tiles) ----
    const f32x4 zz = {0.f, 0.f, 0.f, 0.f};
    #pragma unroll
    for (int s = 0; s < 2; ++s) {
        f32x4 E0 = zz, E1 = zz;
        const float* xrow = inp + ((long)b * Tt + t0 + s * 16) * Ff;
        #pragma unroll
        for (int kt = 0; kt < 4; ++kt) {
            const int f0 = kt * 32 + q * 8;
            float4 a0v = *(const float4*)&xrow[n * Ff + f0];
            float4 a1v = *(const float4*)&xrow[n * Ff + f0 + 4];
            uint4 ua = make_uint4(bfpk2(a0v.x, a0v.y), bfpk2(a0v.z, a0v.w),
                                  bfpk2(a1v.x, a1v.y), bfpk2(a1v.z, a1v.w));
            bf16x8 Aw = __builtin_bit_cast(bf16x8, ua);
            E0 = __builtin_amdgcn_mfma_f32_16x16x32_bf16(Aw, Wlo[kt], E0, 0, 0, 0);
            E1 = __builtin_amdgcn_mfma_f32_16x16x32_bf16(Aw, Whi[kt], E1, 0, 0, 0);
        }
        #pragma unroll
        for (int r = 0; r < 4; ++r) {
            gl[(s * 16 + q * 4 + r) * KE + n]      = __expf(E0[r] - LOG32);
            gl[(s * 16 + q * 4 + r) * KE + 16 + n] = __expf(E1[r] - LOG32);
        }
    }

    // ---- E^T in f32 regs for the A-side: A[m=c32][k] = E^T[m][k] = exp(trans[k][m])
    // lane covers k in {8hi..8hi+7} (lo half) and {16+8hi..16+8hi+7} (hi half)
    float Elo[8], Ehi[8];
    #pragma unroll
    for (int j = 0; j < 8; ++j) {
        Elo[j] = __expf(trans[(8 * hi + j) * Kk + c32]);
        Ehi[j] = __expf(trans[(16 + 8 * hi + j) * Kk + c32]);
    }

    // ---- S = I as 32x32 B-fragments (B[k][col]: col=c32, k=8hi+j / 16+8hi+j) ----
    unsigned B1[4], B2[4];
    #pragma unroll
    for (int w2 = 0; w2 < 4; ++w2) {
        const int r0 = 8 * hi + 2 * w2;
        B1[w2] = (r0 == c32 ? 0x3f80u : 0u) | (r0 + 1 == c32 ? (0x3f80u << 16) : 0u);
        const int r2 = 16 + r0;
        B2[w2] = (r2 == c32 ? 0x3f80u : 0u) | (r2 + 1 == c32 ? (0x3f80u << 16) : 0u);
    }

    // ---- register-resident chain: 32 steps, no LDS round trip ----
    #pragma unroll
    for (int ls = 0; ls < 32; ++ls) {
        if (!((mbits >> ls) & 1u)) continue;          // masked: S unchanged
        const float g = gl[ls * KE + c32];            // broadcast read, conflict-free
        // F = diag(g) * E^T as bf16 A-frags (prep is off the MFMA critical path)
        uint4 fa = make_uint4(bfpk2(g * Elo[0], g * Elo[1]), bfpk2(g * Elo[2], g * Elo[3]),
                              bfpk2(g * Elo[4], g * Elo[5]), bfpk2(g * Elo[6], g * Elo[7]));
        uint4 fb = make_uint4(bfpk2(g * Ehi[0], g * Ehi[1]), bfpk2(g * Ehi[2], g * Ehi[3]),
                              bfpk2(g * Ehi[4], g * Ehi[5]), bfpk2(g * Ehi[6], g * Ehi[7]));
        bf16x8 Alo = __builtin_bit_cast(bf16x8, fa);
        bf16x8 Ahi = __builtin_bit_cast(bf16x8, fb);
        uint4 ub1 = make_uint4(B1[0], B1[1], B1[2], B1[3]);
        uint4 ub2 = make_uint4(B2[0], B2[1], B2[2], B2[3]);
        f32x16 Cc = {0.f, 0.f, 0.f, 0.f, 0.f, 0.f, 0.f, 0.f,
                     0.f, 0.f, 0.f, 0.f, 0.f, 0.f, 0.f, 0.f};
        Cc = __builtin_amdgcn_mfma_f32_32x32x16_bf16(Alo, __builtin_bit_cast(bf16x8, ub1), Cc, 0, 0, 0);
        Cc = __builtin_amdgcn_mfma_f32_32x32x16_bf16(Ahi, __builtin_bit_cast(bf16x8, ub2), Cc, 0, 0, 0);
        // C -> next B-frags: pack row-pairs, then 4 permlane32_swap.
        // C rows per lane: regs 0-3 -> 4hi+0..3, 4-7 -> 8+4hi+0..3,
        //                  8-11 -> 16+4hi+0..3, 12-15 -> 24+4hi+0..3
        unsigned wa = bfpk2(Cc[0], Cc[1]),   wb = bfpk2(Cc[2], Cc[3]);
        unsigned xa = bfpk2(Cc[4], Cc[5]),   xb = bfpk2(Cc[6], Cc[7]);
        unsigned ya = bfpk2(Cc[8], Cc[9]),   yb = bfpk2(Cc[10], Cc[11]);
        unsigned za = bfpk2(Cc[12], Cc[13]), zb = bfpk2(Cc[14], Cc[15]);
        plswap(wa, xa); B1[0] = wa; B1[2] = xa;   // rows 8hi+{0,1} / {4,5}
        plswap(wb, xb); B1[1] = wb; B1[3] = xb;   // rows 8hi+{2,3} / {6,7}
        plswap(ya, za); B2[0] = ya; B2[2] = za;   // rows 16+8hi+{0,1} / {4,5}
        plswap(yb, zb); B2[1] = yb; B2[3] = zb;   // rows 16+8hi+{2,3} / {6,7}
    }

    // ---- store S = M_c straight from B-frags: sq[row*32 + col] ----
    // each u16-store instr writes two contiguous 64B row segments (coalesced)
    unsigned short* sq = SQ + (long)(b * 32 + c) * 1024;
    #pragma unroll
    for (int w2 = 0; w2 < 4; ++w2) {
        const int r0 = 8 * hi + 2 * w2;
        sq[ r0      * 32 + c32] = (unsigned short)(B1[w2] & 0xffffu);
        sq[(r0 + 1) * 32 + c32] = (unsigned short)(B1[w2] >> 16);
        const int r2 = 16 + r0;
        sq[ r2      * 32 + c32] = (unsigned short)(B2[w2] & 0xffffu);
        sq[(r2 + 1) * 32 + c32] = (unsigned short)(B2[w2] >> 16);
    }
}

// ---------------------------------------------------------------------------
// Kernel 2 (phase B): per batch, p^T <- p^T Q_c for c = 0..31.
// Two-deep prefetch; single mid-point rescale (drift stays inside fp32).
// ---------------------------------------------------------------------------
__global__ __launch_bounds__(64) void apply_kernel(
    const float* __restrict__ inp, const int* __restrict__ mask,
    const float* __restrict__ W, const unsigned short* __restrict__ SQ,
    float* __restrict__ out)
{
    const int b = blockIdx.x, lane = threadIdx.x & 63, k = lane & 31;
    const int* mbp = mask + (long)b * Tt;

    const unsigned short* sqb = SQ + (long)b * 32 * 1024;
    uint4 cur[4], nxt[4];
    #pragma unroll
    for (int e = 0; e < 4; ++e) cur[e] = *(const uint4*)(sqb + k * 32 + 8 * e);
    #pragma unroll
    for (int e = 0; e < 4; ++e) nxt[e] = *(const uint4*)(sqb + 1024 + k * 32 + 8 * e);

    // count applied steps (t = 1..1023 with mask != 0)
    int cnt = 0;
    #pragma unroll
    for (int it = 0; it < 16; ++it) cnt += (mbp[it * 64 + lane] != 0) ? 1 : 0;
    #pragma unroll
    for (int off = 32; off; off >>= 1) cnt += __shfl_xor(cnt, off);
    cnt -= (mbp[0] != 0) ? 1 : 0;

    // alpha0[k] = dot(inp[b,0,:], W[:,k]) in fp32
    const float* x0 = inp + (long)b * Tt * Ff;
    float a0 = 0.f;
    #pragma unroll 4
    for (int f = 0; f < Ff; ++f)
        a0 = fmaf(x0[f], W[f * Kk + k], a0);

    float c0 = __int_as_float(__builtin_amdgcn_readlane(__float_as_int(a0), 0));
    float p = __expf(a0 - c0);
    float csum = c0 + (float)cnt * LOG32;

    #pragma unroll 2
    for (int c = 0; c < 32; ++c) {
        uint4 pf[4];
        if (c + 2 < 32) {
            const unsigned short* s2 = sqb + (c + 2) * 1024 + k * 32;
            #pragma unroll
            for (int e = 0; e < 4; ++e) pf[e] = *(const uint4*)(s2 + 8 * e);
        }
        const int pi = __float_as_int(p);
        float q0 = 0.f, q1 = 0.f, q2 = 0.f, q3 = 0.f;
        #define RL(j) __int_as_float(__builtin_amdgcn_readlane(pi, (j)))
        #define ACC2(word, j, acc) \
            acc = fmaf(bf2f((word) & 0xffffu), RL(j), acc); \
            acc = fmaf(bf2f((word) >> 16),     RL((j) + 1), acc);
        ACC2(cur[0].x,  0, q0) ACC2(cur[0].y,  2, q0) ACC2(cur[0].z,  4, q0) ACC2(cur[0].w,  6, q0)
        ACC2(cur[1].x,  8, q1) ACC2(cur[1].y, 10, q1) ACC2(cur[1].z, 12, q1) ACC2(cur[1].w, 14, q1)
        ACC2(cur[2].x, 16, q2) ACC2(cur[2].y, 18, q2) ACC2(cur[2].z, 20, q2) ACC2(cur[2].w, 22, q2)
        ACC2(cur[3].x, 24, q3) ACC2(cur[3].y, 26, q3) ACC2(cur[3].z, 28, q3) ACC2(cur[3].w, 30, q3)
        #undef ACC2
        #undef RL
        float qq = (q0 + q1) + (q2 + q3);
        if (c == 15) {   // single mid-point rescale keeps p well inside fp32
            float s0 = __int_as_float(__builtin_amdgcn_readlane(__float_as_int(qq), 0));
            csum += __logf(s0);
            qq *= (1.0f / s0);
        }
        p = qq;
        #pragma unroll
        for (int e = 0; e < 4; ++e) { cur[e] = nxt[e]; nxt[e] = pf[e]; }
    }

    float sum = p;
    #pragma unroll
    for (int off = 16; off > 0; off >>= 1)
        sum += __shfl_xor(sum, off);
    if (lane == 0)
        atomicAdd(out, csum + __logf(sum));
}

extern "C" void kernel_launch(void* const* d_in, const int* in_sizes, int n_in,
                              void* d_out, int out_size, void* d_ws, size_t ws_size,
                              hipStream_t stream)
{
    const float* inp   = (const float*)d_in[0];
    const int*   mask  = (const int*)d_in[1];
    const float* W     = (const float*)d_in[2];
    const float* trans = (const float*)d_in[3];
    float* out = (float*)d_out;
    unsigned short* SQ = (unsigned short*)d_ws;   // 128*32 chunk matrices * 2 KB = 8 MB

    chunk_kernel<<<dim3(Bb * 32), dim3(64), 0, stream>>>(inp, mask, W, trans, SQ, out);
    apply_kernel<<<dim3(Bb), dim3(64), 0, stream>>>(inp, mask, W, SQ, out);
}

// Round 2
// 134.026 us; speedup vs baseline: 1.0111x; 1.0111x over previous
//
#include <hip/hip_runtime.h>
#include <hip/hip_bf16.h>

#define Bb 128
#define Tt 1024
#define Ff 128
#define Kk 32
#define KE 36          // g LDS row stride (floats)
#define LOG32 3.4657359027997265f

typedef __attribute__((ext_vector_type(8))) short bf16x8;
typedef __attribute__((ext_vector_type(4))) float f32x4;
typedef __attribute__((ext_vector_type(16))) float f32x16;

__device__ __forceinline__ float bf2f(unsigned u) {
    return __uint_as_float(u << 16);
}
// packed f32x2 -> bf16x2 (v_cvt_pk_bf16_f32 on gfx950)
__device__ __forceinline__ unsigned bfpk2(float a, float b) {
    __hip_bfloat162 h = __float22bfloat162_rn(make_float2(a, b));
    unsigned u;
    __builtin_memcpy(&u, &h, sizeof(u));
    return u;
}
// v_permlane32_swap_b32: a.hi-lanes <-> b.lo-lanes.
__device__ __forceinline__ void plswap(unsigned &a, unsigned &b) {
    asm("v_permlane32_swap_b32 %0, %1" : "+v"(a), "+v"(b));
}

// ---------------------------------------------------------------------------
// Kernel 1: one 64-lane wave per (batch, chunk-of-32-steps).
//   Register-resident chain (32x32x16 MFMA, permlane relayout) as in the
//   passing version; emission split so tile-1's global loads are issued
//   BEFORE chain steps 0-15 and land under ~2000cy of chain VALU/MFMA.
//   S stored to SQ as f32 (unpacked from bf16 words -> values identical,
//   moves the unpack off apply_kernel's serial path).
// ---------------------------------------------------------------------------
__global__ __launch_bounds__(64, 3) void chunk_kernel(
    const float* __restrict__ inp, const int* __restrict__ mask,
    const float* __restrict__ W, const float* __restrict__ trans,
    float* __restrict__ SQ, float* __restrict__ out)
{
    __shared__ __align__(16) float gl[32 * KE];
    const int lane = threadIdx.x & 63;
    const int q = (lane >> 4) & 3, n = lane & 15;   // 16x16 emission indexing
    const int c32 = lane & 31, hi = lane >> 5;      // 32x32 chain indexing
    const int b = blockIdx.x >> 5, c = blockIdx.x & 31;
    const int t0 = c * 32;

    if (blockIdx.x == 0 && lane == 0) out[0] = 0.f;

    // 32-step mask bits (t=0 is the init state, never a step)
    const int* mbp = mask + (long)b * Tt;
    unsigned mbits = (unsigned)__ballot(mbp[t0 + c32] != 0);  // bit l == bit l+32
    if (c == 0) mbits &= ~1u;

    // ---- tile-0 x loads first (in flight during W prep) ----
    const float* xrow = inp + ((long)b * Tt + t0) * Ff;
    float4 x0r[8];
    #pragma unroll
    for (int kt = 0; kt < 4; ++kt) {
        x0r[2 * kt]     = *(const float4*)&xrow[n * Ff + kt * 32 + q * 8];
        x0r[2 * kt + 1] = *(const float4*)&xrow[n * Ff + kt * 32 + q * 8 + 4];
    }

    // ---- W bf16 fragments, hoisted once ----
    bf16x8 Wlo[4], Whi[4];
    #pragma unroll
    for (int kt = 0; kt < 4; ++kt) {
        const int f0 = kt * 32 + q * 8;
        float wl[8], wh[8];
        #pragma unroll
        for (int jj = 0; jj < 8; ++jj) {
            wl[jj] = W[(f0 + jj) * Kk + n];
            wh[jj] = W[(f0 + jj) * Kk + 16 + n];
        }
        uint4 uc = make_uint4(bfpk2(wl[0], wl[1]), bfpk2(wl[2], wl[3]),
                              bfpk2(wl[4], wl[5]), bfpk2(wl[6], wl[7]));
        uint4 ud = make_uint4(bfpk2(wh[0], wh[1]), bfpk2(wh[2], wh[3]),
                              bfpk2(wh[4], wh[5]), bfpk2(wh[6], wh[7]));
        Wlo[kt] = __builtin_bit_cast(bf16x8, uc);
        Whi[kt] = __builtin_bit_cast(bf16x8, ud);
    }

    const f32x4 zz = {0.f, 0.f, 0.f, 0.f};

    // ---- tile-0 emission (rows t0..t0+15) ----
    {
        f32x4 E0 = zz, E1 = zz;
        #pragma unroll
        for (int kt = 0; kt < 4; ++kt) {
            float4 a0v = x0r[2 * kt], a1v = x0r[2 * kt + 1];
            uint4 ua = make_uint4(bfpk2(a0v.x, a0v.y), bfpk2(a0v.z, a0v.w),
                                  bfpk2(a1v.x, a1v.y), bfpk2(a1v.z, a1v.w));
            bf16x8 Aw = __builtin_bit_cast(bf16x8, ua);
            E0 = __builtin_amdgcn_mfma_f32_16x16x32_bf16(Aw, Wlo[kt], E0, 0, 0, 0);
            E1 = __builtin_amdgcn_mfma_f32_16x16x32_bf16(Aw, Whi[kt], E1, 0, 0, 0);
        }
        #pragma unroll
        for (int r = 0; r < 4; ++r) {
            gl[(q * 4 + r) * KE + n]      = __expf(E0[r] - LOG32);
            gl[(q * 4 + r) * KE + 16 + n] = __expf(E1[r] - LOG32);
        }
    }

    // ---- issue tile-1 x loads now; they land under chain steps 0-15 ----
    float4 x1r[8];
    #pragma unroll
    for (int kt = 0; kt < 4; ++kt) {
        x1r[2 * kt]     = *(const float4*)&xrow[(16 + n) * Ff + kt * 32 + q * 8];
        x1r[2 * kt + 1] = *(const float4*)&xrow[(16 + n) * Ff + kt * 32 + q * 8 + 4];
    }

    // ---- E^T in f32 regs for the A-side ----
    float Elo[8], Ehi[8];
    #pragma unroll
    for (int j = 0; j < 8; ++j) {
        Elo[j] = __expf(trans[(8 * hi + j) * Kk + c32]);
        Ehi[j] = __expf(trans[(16 + 8 * hi + j) * Kk + c32]);
    }

    // ---- S = I as 32x32 B-fragments ----
    unsigned B1[4], B2[4];
    #pragma unroll
    for (int w2 = 0; w2 < 4; ++w2) {
        const int r0 = 8 * hi + 2 * w2;
        B1[w2] = (r0 == c32 ? 0x3f80u : 0u) | (r0 + 1 == c32 ? (0x3f80u << 16) : 0u);
        const int r2 = 16 + r0;
        B2[w2] = (r2 == c32 ? 0x3f80u : 0u) | (r2 + 1 == c32 ? (0x3f80u << 16) : 0u);
    }

    auto chain_step = [&](int ls) {
        if (!((mbits >> ls) & 1u)) return;            // masked: S unchanged
        const float g = gl[ls * KE + c32];            // broadcast read, conflict-free
        uint4 fa = make_uint4(bfpk2(g * Elo[0], g * Elo[1]), bfpk2(g * Elo[2], g * Elo[3]),
                              bfpk2(g * Elo[4], g * Elo[5]), bfpk2(g * Elo[6], g * Elo[7]));
        uint4 fb = make_uint4(bfpk2(g * Ehi[0], g * Ehi[1]), bfpk2(g * Ehi[2], g * Ehi[3]),
                              bfpk2(g * Ehi[4], g * Ehi[5]), bfpk2(g * Ehi[6], g * Ehi[7]));
        bf16x8 Alo = __builtin_bit_cast(bf16x8, fa);
        bf16x8 Ahi = __builtin_bit_cast(bf16x8, fb);
        uint4 ub1 = make_uint4(B1[0], B1[1], B1[2], B1[3]);
        uint4 ub2 = make_uint4(B2[0], B2[1], B2[2], B2[3]);
        f32x16 Cc = {0.f, 0.f, 0.f, 0.f, 0.f, 0.f, 0.f, 0.f,
                     0.f, 0.f, 0.f, 0.f, 0.f, 0.f, 0.f, 0.f};
        Cc = __builtin_amdgcn_mfma_f32_32x32x16_bf16(Alo, __builtin_bit_cast(bf16x8, ub1), Cc, 0, 0, 0);
        Cc = __builtin_amdgcn_mfma_f32_32x32x16_bf16(Ahi, __builtin_bit_cast(bf16x8, ub2), Cc, 0, 0, 0);
        unsigned wa = bfpk2(Cc[0], Cc[1]),   wb = bfpk2(Cc[2], Cc[3]);
        unsigned xa = bfpk2(Cc[4], Cc[5]),   xb = bfpk2(Cc[6], Cc[7]);
        unsigned ya = bfpk2(Cc[8], Cc[9]),   yb = bfpk2(Cc[10], Cc[11]);
        unsigned za = bfpk2(Cc[12], Cc[13]), zb = bfpk2(Cc[14], Cc[15]);
        plswap(wa, xa); B1[0] = wa; B1[2] = xa;
        plswap(wb, xb); B1[1] = wb; B1[3] = xb;
        plswap(ya, za); B2[0] = ya; B2[2] = za;
        plswap(yb, zb); B2[1] = yb; B2[3] = zb;
    };

    // ---- chain steps 0..15 (tile-1 loads in flight) ----
    #pragma unroll
    for (int ls = 0; ls < 16; ++ls) chain_step(ls);

    // ---- tile-1 emission (rows t0+16..t0+31) ----
    {
        f32x4 E0 = zz, E1 = zz;
        #pragma unroll
        for (int kt = 0; kt < 4; ++kt) {
            float4 a0v = x1r[2 * kt], a1v = x1r[2 * kt + 1];
            uint4 ua = make_uint4(bfpk2(a0v.x, a0v.y), bfpk2(a0v.z, a0v.w),
                                  bfpk2(a1v.x, a1v.y), bfpk2(a1v.z, a1v.w));
            bf16x8 Aw = __builtin_bit_cast(bf16x8, ua);
            E0 = __builtin_amdgcn_mfma_f32_16x16x32_bf16(Aw, Wlo[kt], E0, 0, 0, 0);
            E1 = __builtin_amdgcn_mfma_f32_16x16x32_bf16(Aw, Whi[kt], E1, 0, 0, 0);
        }
        #pragma unroll
        for (int r = 0; r < 4; ++r) {
            gl[(16 + q * 4 + r) * KE + n]      = __expf(E0[r] - LOG32);
            gl[(16 + q * 4 + r) * KE + 16 + n] = __expf(E1[r] - LOG32);
        }
    }

    // ---- chain steps 16..31 ----
    #pragma unroll
    for (int ls = 16; ls < 32; ++ls) chain_step(ls);

    // ---- store S = M_c as f32 (values identical to the bf16 words) ----
    float* sq = SQ + (long)(b * 32 + c) * 1024;
    #pragma unroll
    for (int w2 = 0; w2 < 4; ++w2) {
        const int r0 = 8 * hi + 2 * w2;
        sq[ r0      * 32 + c32] = bf2f(B1[w2] & 0xffffu);
        sq[(r0 + 1) * 32 + c32] = bf2f(B1[w2] >> 16);
        const int r2 = 16 + r0;
        sq[ r2      * 32 + c32] = bf2f(B2[w2] & 0xffffu);
        sq[(r2 + 1) * 32 + c32] = bf2f(B2[w2] >> 16);
    }
}

// ---------------------------------------------------------------------------
// Kernel 2 (phase B): per batch, p^T <- p^T Q_c for c = 0..31.
// f32 SQ (no bf16 unpack on the serial path), 4-deep register prefetch,
// single mid-point rescale. Math identical to the passing version.
// ---------------------------------------------------------------------------
__global__ __launch_bounds__(64) void apply_kernel(
    const float* __restrict__ inp, const int* __restrict__ mask,
    const float* __restrict__ W, const float* __restrict__ SQ,
    float* __restrict__ out)
{
    const int b = blockIdx.x, lane = threadIdx.x & 63, k = lane & 31;
    const float* sqb = SQ + (long)b * 32 * 1024 + k * 32;

    // prologue: fill all 4 prefetch buffers (in flight during cnt + alpha0 dot)
    float Qb[4][32];
    #pragma unroll
    for (int pc = 0; pc < 4; ++pc) {
        #pragma unroll
        for (int e = 0; e < 8; ++e)
            *(float4*)&Qb[pc][4 * e] = *(const float4*)(sqb + pc * 1024 + 4 * e);
    }

    const int* mbp = mask + (long)b * Tt;
    int cnt = 0;
    #pragma unroll
    for (int it = 0; it < 16; ++it) cnt += (mbp[it * 64 + lane] != 0) ? 1 : 0;
    #pragma unroll
    for (int off = 32; off; off >>= 1) cnt += __shfl_xor(cnt, off);
    cnt -= (mbp[0] != 0) ? 1 : 0;

    // alpha0[k] = dot(inp[b,0,:], W[:,k]) in fp32, 4 accumulators
    const float* x0 = inp + (long)b * Tt * Ff;
    float a0 = 0.f, a1 = 0.f, a2 = 0.f, a3 = 0.f;
    #pragma unroll 8
    for (int f = 0; f < Ff; f += 4) {
        a0 = fmaf(x0[f],     W[f * Kk + k],       a0);
        a1 = fmaf(x0[f + 1], W[(f + 1) * Kk + k], a1);
        a2 = fmaf(x0[f + 2], W[(f + 2) * Kk + k], a2);
        a3 = fmaf(x0[f + 3], W[(f + 3) * Kk + k], a3);
    }
    float av = (a0 + a1) + (a2 + a3);

    float c0 = __int_as_float(__builtin_amdgcn_readlane(__float_as_int(av), 0));
    float p = __expf(av - c0);
    float csum = c0 + (float)cnt * LOG32;

    #define RLX(j) __int_as_float(__builtin_amdgcn_readlane(pi, (j)))
    for (int co = 0; co < 8; ++co) {
        #pragma unroll
        for (int ci = 0; ci < 4; ++ci) {
            const int cc = co * 4 + ci;
            const int pi = __float_as_int(p);
            float q0 = 0.f, q1 = 0.f, q2 = 0.f, q3 = 0.f;
            #pragma unroll
            for (int j = 0; j < 8; ++j) {
                q0 = fmaf(Qb[ci][j],      RLX(j),      q0);
                q1 = fmaf(Qb[ci][8 + j],  RLX(8 + j),  q1);
                q2 = fmaf(Qb[ci][16 + j], RLX(16 + j), q2);
                q3 = fmaf(Qb[ci][24 + j], RLX(24 + j), q3);
            }
            float qq = (q0 + q1) + (q2 + q3);
            // refill this buffer for chunk cc+4 (3 iterations of latency cover)
            if (cc < 28) {
                const float* s4 = sqb + (cc + 4) * 1024;
                #pragma unroll
                for (int e = 0; e < 8; ++e)
                    *(float4*)&Qb[ci][4 * e] = *(const float4*)(s4 + 4 * e);
            }
            if (cc == 15) {   // single mid-point rescale keeps p inside fp32
                float s0 = __int_as_float(__builtin_amdgcn_readlane(__float_as_int(qq), 0));
                csum += __logf(s0);
                qq *= (1.0f / s0);
            }
            p = qq;
        }
    }
    #undef RLX

    float sum = p;
    #pragma unroll
    for (int off = 16; off > 0; off >>= 1)
        sum += __shfl_xor(sum, off);
    if (lane == 0)
        atomicAdd(out, csum + __logf(sum));
}

extern "C" void kernel_launch(void* const* d_in, const int* in_sizes, int n_in,
                              void* d_out, int out_size, void* d_ws, size_t ws_size,
                              hipStream_t stream)
{
    const float* inp   = (const float*)d_in[0];
    const int*   mask  = (const int*)d_in[1];
    const float* W     = (const float*)d_in[2];
    const float* trans = (const float*)d_in[3];
    float* out = (float*)d_out;
    float* SQ = (float*)d_ws;   // 128*32 chunk matrices * 4 KB = 16 MB

    chunk_kernel<<<dim3(Bb * 32), dim3(64), 0, stream>>>(inp, mask, W, trans, SQ, out);
    apply_kernel<<<dim3(Bb), dim3(64), 0, stream>>>(inp, mask, W, SQ, out);
}

// Round 3
// 129.106 us; speedup vs baseline: 1.0497x; 1.0381x over previous
//
#include <hip/hip_runtime.h>
#include <hip/hip_bf16.h>

#define Bb 128
#define Tt 1024
#define Ff 128
#define Kk 32
#define KS 36          // S LDS row stride (bf16 elems): 72 B, divisible by 8
#define KE 36          // g LDS row stride (floats)
#define LOG32 3.4657359027997265f

typedef __attribute__((ext_vector_type(8))) short bf16x8;
typedef __attribute__((ext_vector_type(4))) float f32x4;

__device__ __forceinline__ float bf2f(unsigned u) {
    return __uint_as_float(u << 16);
}
__device__ __forceinline__ unsigned short f2bf(float f) {
    unsigned u = __float_as_uint(f);
    u = (u + 0x7fffu + ((u >> 16) & 1u)) >> 16;      // RNE
    return (unsigned short)u;
}
// packed f32x2 -> bf16x2 (v_cvt_pk_bf16_f32 on gfx950)
__device__ __forceinline__ unsigned bfpk2(float a, float b) {
    __hip_bfloat162 h = __float22bfloat162_rn(make_float2(a, b));
    unsigned u;
    __builtin_memcpy(&u, &h, sizeof(u));
    return u;
}

// ---------------------------------------------------------------------------
// Kernel 1: per (batch, chunk) block of 2 waves.
//   Wave w handles global steps tw = c*32 + w*16 .. tw+15:
//     emission rows tw..tw+15 via 8 MFMAs -> g = exp(em-log32) in shared gl;
//     half-chain S_w <- diag(g_t)*(E^T*S_w) over its unmasked steps (16 deep).
//   Barrier, then combine Q^T = S_b * S_a with one K=32 MFMA per tile
//   (wave w computes rows w*16..w*16+15) and store straight to SQ.
// Serial LDS-round-trip depth: 16 + 1 instead of 32.
// ---------------------------------------------------------------------------
__global__ __launch_bounds__(128, 4) void chunk_kernel(
    const float* __restrict__ inp, const int* __restrict__ mask,
    const float* __restrict__ W, const float* __restrict__ trans,
    unsigned short* __restrict__ SQ, float* __restrict__ out)
{
    __shared__ __align__(16) float gl[32 * KE];
    __shared__ __align__(16) unsigned short Sl[2][32 * KS];
    const int tid = threadIdx.x;
    const int w = tid >> 6, lane = tid & 63;
    const int q = lane >> 4, n = lane & 15;
    const int b = blockIdx.x >> 5, c = blockIdx.x & 31;
    const int tw = c * 32 + w * 16;

    if (blockIdx.x == 0 && tid == 0) out[0] = 0.f;

    // this wave's 16-step mask bits (t=0 is the init state, never a step)
    const int* mbp = mask + (long)b * Tt;
    int mybit = (lane < 16) ? (mbp[tw + lane] != 0) : 0;
    unsigned mbits = (unsigned)__ballot(mybit) & 0xffffu;
    if (c == 0 && w == 0) mbits &= ~1u;

    // Fixed A-operand for the chain: A_i[j] = E^T[i*16+n][q*8+j]
    bf16x8 A0, A1;
    #pragma unroll
    for (int j = 0; j < 8; ++j) {
        A0[j] = (short)f2bf(__expf(trans[(q * 8 + j) * Kk + n]));
        A1[j] = (short)f2bf(__expf(trans[(q * 8 + j) * Kk + 16 + n]));
    }

    // ---- emission rows tw..tw+15 via MFMA ----
    const f32x4 zz = {0.f, 0.f, 0.f, 0.f};
    f32x4 E0 = zz, E1 = zz;
    const float* xrow = inp + ((long)b * Tt + tw) * Ff;
    #pragma unroll
    for (int kt = 0; kt < 4; ++kt) {
        const int f0 = kt * 32 + q * 8;
        float4 a0v = *(const float4*)&xrow[n * Ff + f0];
        float4 a1v = *(const float4*)&xrow[n * Ff + f0 + 4];
        uint4 ua = make_uint4(bfpk2(a0v.x, a0v.y), bfpk2(a0v.z, a0v.w),
                              bfpk2(a1v.x, a1v.y), bfpk2(a1v.z, a1v.w));
        bf16x8 Aw = __builtin_bit_cast(bf16x8, ua);
        float wl[8], wh[8];
        #pragma unroll
        for (int jj = 0; jj < 8; ++jj) {
            wl[jj] = W[(f0 + jj) * Kk + n];
            wh[jj] = W[(f0 + jj) * Kk + 16 + n];
        }
        uint4 uc = make_uint4(bfpk2(wl[0], wl[1]), bfpk2(wl[2], wl[3]),
                              bfpk2(wl[4], wl[5]), bfpk2(wl[6], wl[7]));
        uint4 ud = make_uint4(bfpk2(wh[0], wh[1]), bfpk2(wh[2], wh[3]),
                              bfpk2(wh[4], wh[5]), bfpk2(wh[6], wh[7]));
        bf16x8 Blo = __builtin_bit_cast(bf16x8, uc);
        bf16x8 Bhi = __builtin_bit_cast(bf16x8, ud);
        E0 = __builtin_amdgcn_mfma_f32_16x16x32_bf16(Aw, Blo, E0, 0, 0, 0);
        E1 = __builtin_amdgcn_mfma_f32_16x16x32_bf16(Aw, Bhi, E1, 0, 0, 0);
    }
    #pragma unroll
    for (int r = 0; r < 4; ++r) {
        gl[(w * 16 + q * 4 + r) * KE + n]      = __expf(E0[r] - LOG32);
        gl[(w * 16 + q * 4 + r) * KE + 16 + n] = __expf(E1[r] - LOG32);
    }

    // ---- S_w = I (column-major bf16, stride KS) ----
    unsigned short* Sw = Sl[w];
    for (int i = lane; i < (32 * KS) / 2; i += 64)
        ((unsigned*)Sw)[i] = 0u;
    if (lane < 32) Sw[lane * KS + lane] = 0x3f80;

    #pragma unroll
    for (int ls = 0; ls < 16; ++ls) {
        if (!((mbits >> ls) & 1u)) continue;      // masked: S unchanged (SALU)
        // B-frags: B[k][col] = S[k][col] = Sw[col*KS + k], k = q*8+jj
        uint2 xa = *(const uint2*)&Sw[ n       * KS + q * 8];
        uint2 xb = *(const uint2*)&Sw[ n       * KS + q * 8 + 4];
        uint2 ya = *(const uint2*)&Sw[(n + 16) * KS + q * 8];
        uint2 yb = *(const uint2*)&Sw[(n + 16) * KS + q * 8 + 4];
        uint4 u0 = make_uint4(xa.x, xa.y, xb.x, xb.y);
        uint4 u1 = make_uint4(ya.x, ya.y, yb.x, yb.y);
        bf16x8 B0 = __builtin_bit_cast(bf16x8, u0);
        bf16x8 B1 = __builtin_bit_cast(bf16x8, u1);
        f32x4 D00 = __builtin_amdgcn_mfma_f32_16x16x32_bf16(A0, B0, zz, 0, 0, 0);
        f32x4 D01 = __builtin_amdgcn_mfma_f32_16x16x32_bf16(A0, B1, zz, 0, 0, 0);
        f32x4 D10 = __builtin_amdgcn_mfma_f32_16x16x32_bf16(A1, B0, zz, 0, 0, 0);
        f32x4 D11 = __builtin_amdgcn_mfma_f32_16x16x32_bf16(A1, B1, zz, 0, 0, 0);
        float4 g0 = *(const float4*)&gl[(w * 16 + ls) * KE + q * 4];
        float4 g1 = *(const float4*)&gl[(w * 16 + ls) * KE + 16 + q * 4];
        *(uint2*)&Sw[ n       * KS      + q * 4] =
            make_uint2(bfpk2(D00[0] * g0.x, D00[1] * g0.y), bfpk2(D00[2] * g0.z, D00[3] * g0.w));
        *(uint2*)&Sw[(n + 16) * KS      + q * 4] =
            make_uint2(bfpk2(D01[0] * g0.x, D01[1] * g0.y), bfpk2(D01[2] * g0.z, D01[3] * g0.w));
        *(uint2*)&Sw[ n       * KS + 16 + q * 4] =
            make_uint2(bfpk2(D10[0] * g1.x, D10[1] * g1.y), bfpk2(D10[2] * g1.z, D10[3] * g1.w));
        *(uint2*)&Sw[(n + 16) * KS + 16 + q * 4] =
            make_uint2(bfpk2(D11[0] * g1.x, D11[1] * g1.y), bfpk2(D11[2] * g1.z, D11[3] * g1.w));
    }

    __syncthreads();

    // ---- combine: Q^T = S_b * S_a ; wave w computes rows w*16..w*16+15 ----
    const unsigned short* SlA = Sl[0];   // S_a (steps 0..15)
    const unsigned short* SlB = Sl[1];   // S_b (steps 16..31)
    bf16x8 Af;
    #pragma unroll
    for (int j = 0; j < 8; ++j)                 // A[m][k] = S_b[w*16+n][k]
        Af[j] = (short)SlB[(q * 8 + j) * KS + w * 16 + n];
    uint2 xa = *(const uint2*)&SlA[ n       * KS + q * 8];
    uint2 xb = *(const uint2*)&SlA[ n       * KS + q * 8 + 4];
    uint2 ya = *(const uint2*)&SlA[(n + 16) * KS + q * 8];
    uint2 yb = *(const uint2*)&SlA[(n + 16) * KS + q * 8 + 4];
    uint4 u0 = make_uint4(xa.x, xa.y, xb.x, xb.y);
    uint4 u1 = make_uint4(ya.x, ya.y, yb.x, yb.y);
    bf16x8 B0 = __builtin_bit_cast(bf16x8, u0);
    bf16x8 B1 = __builtin_bit_cast(bf16x8, u1);
    f32x4 D0 = __builtin_amdgcn_mfma_f32_16x16x32_bf16(Af, B0, zz, 0, 0, 0);
    f32x4 D1 = __builtin_amdgcn_mfma_f32_16x16x32_bf16(Af, B1, zz, 0, 0, 0);

    // store straight from C-layout: sq[row*32 + col], row = w*16+q*4+r
    unsigned short* sq = SQ + (long)(b * 32 + c) * 1024;
    #pragma unroll
    for (int r = 0; r < 4; ++r) {
        sq[(w * 16 + q * 4 + r) * 32 + n]      = f2bf(D0[r]);
        sq[(w * 16 + q * 4 + r) * 32 + 16 + n] = f2bf(D1[r]);
    }
}

// ---------------------------------------------------------------------------
// Kernel 2 (phase B): per batch, p^T <- p^T Q_c for c = 0..31.
// Two-deep prefetch; single mid-point rescale (drift stays inside fp32).
// ---------------------------------------------------------------------------
__global__ __launch_bounds__(64) void apply_kernel(
    const float* __restrict__ inp, const int* __restrict__ mask,
    const float* __restrict__ W, const unsigned short* __restrict__ SQ,
    float* __restrict__ out)
{
    const int b = blockIdx.x, lane = threadIdx.x & 63, k = lane & 31;
    const int* mbp = mask + (long)b * Tt;

    const unsigned short* sqb = SQ + (long)b * 32 * 1024;
    uint4 cur[4], nxt[4];
    #pragma unroll
    for (int e = 0; e < 4; ++e) cur[e] = *(const uint4*)(sqb + k * 32 + 8 * e);
    #pragma unroll
    for (int e = 0; e < 4; ++e) nxt[e] = *(const uint4*)(sqb + 1024 + k * 32 + 8 * e);

    // count applied steps (t = 1..1023 with mask != 0)
    int cnt = 0;
    #pragma unroll
    for (int it = 0; it < 16; ++it) cnt += (mbp[it * 64 + lane] != 0) ? 1 : 0;
    #pragma unroll
    for (int off = 32; off; off >>= 1) cnt += __shfl_xor(cnt, off);
    cnt -= (mbp[0] != 0) ? 1 : 0;

    // alpha0[k] = dot(inp[b,0,:], W[:,k]) in fp32
    const float* x0 = inp + (long)b * Tt * Ff;
    float a0 = 0.f;
    #pragma unroll 4
    for (int f = 0; f < Ff; ++f)
        a0 = fmaf(x0[f], W[f * Kk + k], a0);

    float c0 = __int_as_float(__builtin_amdgcn_readlane(__float_as_int(a0), 0));
    float p = __expf(a0 - c0);
    float csum = c0 + (float)cnt * LOG32;

    #pragma unroll 2
    for (int c = 0; c < 32; ++c) {
        uint4 pf[4];
        if (c + 2 < 32) {
            const unsigned short* s2 = sqb + (c + 2) * 1024 + k * 32;
            #pragma unroll
            for (int e = 0; e < 4; ++e) pf[e] = *(const uint4*)(s2 + 8 * e);
        }
        const int pi = __float_as_int(p);
        float q0 = 0.f, q1 = 0.f, q2 = 0.f, q3 = 0.f;
        #define RL(j) __int_as_float(__builtin_amdgcn_readlane(pi, (j)))
        #define ACC2(word, j, acc) \
            acc = fmaf(bf2f((word) & 0xffffu), RL(j), acc); \
            acc = fmaf(bf2f((word) >> 16),     RL((j) + 1), acc);
        ACC2(cur[0].x,  0, q0) ACC2(cur[0].y,  2, q0) ACC2(cur[0].z,  4, q0) ACC2(cur[0].w,  6, q0)
        ACC2(cur[1].x,  8, q1) ACC2(cur[1].y, 10, q1) ACC2(cur[1].z, 12, q1) ACC2(cur[1].w, 14, q1)
        ACC2(cur[2].x, 16, q2) ACC2(cur[2].y, 18, q2) ACC2(cur[2].z, 20, q2) ACC2(cur[2].w, 22, q2)
        ACC2(cur[3].x, 24, q3) ACC2(cur[3].y, 26, q3) ACC2(cur[3].z, 28, q3) ACC2(cur[3].w, 30, q3)
        #undef ACC2
        #undef RL
        float qq = (q0 + q1) + (q2 + q3);
        if (c == 15) {   // single mid-point rescale keeps p well inside fp32
            float s0 = __int_as_float(__builtin_amdgcn_readlane(__float_as_int(qq), 0));
            csum += __logf(s0);
            qq *= (1.0f / s0);
        }
        p = qq;
        #pragma unroll
        for (int e = 0; e < 4; ++e) { cur[e] = nxt[e]; nxt[e] = pf[e]; }
    }

    float sum = p;
    #pragma unroll
    for (int off = 16; off > 0; off >>= 1)
        sum += __shfl_xor(sum, off);
    if (lane == 0)
        atomicAdd(out, csum + __logf(sum));
}

extern "C" void kernel_launch(void* const* d_in, const int* in_sizes, int n_in,
                              void* d_out, int out_size, void* d_ws, size_t ws_size,
                              hipStream_t stream)
{
    const float* inp   = (const float*)d_in[0];
    const int*   mask  = (const int*)d_in[1];
    const float* W     = (const float*)d_in[2];
    const float* trans = (const float*)d_in[3];
    float* out = (float*)d_out;
    unsigned short* SQ = (unsigned short*)d_ws;   // 128*32 chunk matrices * 2 KB = 8 MB

    chunk_kernel<<<dim3(Bb * 32), dim3(128), 0, stream>>>(inp, mask, W, trans, SQ, out);
    apply_kernel<<<dim3(Bb), dim3(64), 0, stream>>>(inp, mask, W, SQ, out);
}